// Round 10
// baseline (735.680 us; speedup 1.0000x reference)
//
#include <hip/hip_runtime.h>
#include <stdint.h>

// BitNet b1.58 column-parallel linear:
//   y[m,n] = (sum_k qx[m,k]*qw[n,k]) * inv_sx[m] * inv_sw + bias[n]
// M=8192 (B*S), N=16384 (D_OUT), K=4096 (D_IN)

#define M_ROWS 8192
#define N_COLS 16384
#define K_DIM  4096
#define NT     (K_DIM / 64)   // 64 K-steps of 64 bytes

typedef int v4i  __attribute__((ext_vector_type(4)));
typedef int v16i __attribute__((ext_vector_type(16)));

// ---------------- workspace layout ----------------
#define WS_PARTIALS 0
#define WS_PARAMS   8192
#define WS_INVSX    8448
#define WS_QX       41216
#define WS_QW       (41216 + 33554432)
#define WS_NEED     ((size_t)WS_QW + 67108864)

// ---------------- activation quant: per-row int8 absmax ----------------
__device__ __forceinline__ int quant_act1(float v, float s) {
    float q = rintf(v * s);               // round-half-even, matches jnp.round
    q = fminf(127.0f, fmaxf(-128.0f, q));
    return (int)q;
}

__global__ __launch_bounds__(256) void act_quant_kernel(const float* __restrict__ x,
                                                        int8_t* __restrict__ qx,
                                                        float* __restrict__ inv_sx) {
    const int row = blockIdx.x;
    const int t = threadIdx.x;
    const float4* xr = (const float4*)(x + (size_t)row * K_DIM);

    float4 v[4];
    float m = 0.0f;
#pragma unroll
    for (int i = 0; i < 4; ++i) {
        v[i] = xr[t + 256 * i];
        m = fmaxf(m, fmaxf(fmaxf(fabsf(v[i].x), fabsf(v[i].y)),
                           fmaxf(fabsf(v[i].z), fabsf(v[i].w))));
    }
#pragma unroll
    for (int off = 32; off > 0; off >>= 1) m = fmaxf(m, __shfl_xor(m, off));
    __shared__ float wm[4];
    if ((t & 63) == 0) wm[t >> 6] = m;
    __syncthreads();
    m = fmaxf(fmaxf(wm[0], wm[1]), fmaxf(wm[2], wm[3]));
    m = fmaxf(m, 1e-5f);                  // clip(max, EPS)
    const float scale = 127.0f / m;
    if (t == 0) inv_sx[row] = 1.0f / scale;

    int* qr = (int*)(qx + (size_t)row * K_DIM);
#pragma unroll
    for (int i = 0; i < 4; ++i) {
        int b0 = quant_act1(v[i].x, scale) & 255;
        int b1 = quant_act1(v[i].y, scale) & 255;
        int b2 = quant_act1(v[i].z, scale) & 255;
        int b3 = quant_act1(v[i].w, scale) & 255;
        qr[t + 256 * i] = b0 | (b1 << 8) | (b2 << 16) | (b3 << 24);
    }
}

// ---------------- weight abs-sum (deterministic two-stage) ----------------
__global__ __launch_bounds__(256) void wabs_partial_kernel(const float* __restrict__ w,
                                                           float* __restrict__ partials) {
    const int t = threadIdx.x;
    const size_t base = (size_t)blockIdx.x * 8192;   // float4 units
    const float4* w4 = (const float4*)w;
    float s = 0.0f;
#pragma unroll 8
    for (int i = 0; i < 32; ++i) {
        float4 v = w4[base + (size_t)i * 256 + t];
        s += fabsf(v.x) + fabsf(v.y) + fabsf(v.z) + fabsf(v.w);
    }
#pragma unroll
    for (int off = 32; off > 0; off >>= 1) s += __shfl_xor(s, off);
    __shared__ float wp[4];
    if ((t & 63) == 0) wp[t >> 6] = s;
    __syncthreads();
    if (t == 0) partials[blockIdx.x] = (wp[0] + wp[1]) + (wp[2] + wp[3]);
}

__global__ __launch_bounds__(256) void wfinal_kernel(const float* __restrict__ partials,
                                                     float* __restrict__ params) {
    __shared__ double sh[256];
    const int t = threadIdx.x;
    double s = 0.0;
    for (int i = t; i < 2048; i += 256) s += (double)partials[i];
    sh[t] = s;
    __syncthreads();
    for (int off = 128; off > 0; off >>= 1) {
        if (t < off) sh[t] += sh[t + off];
        __syncthreads();
    }
    if (t == 0) {
        float mean = (float)(sh[0] / 67108864.0);
        mean = fmaxf(mean, 1e-5f);        // clip(mean, EPS)
        float scale = 1.0f / mean;        // scale_w
        params[0] = scale;
        params[1] = 1.0f / scale;         // inv_sw
    }
}

// ---------------- weight quant: per-tensor ternary ----------------
__device__ __forceinline__ int quant_w1(float v, float s) {
    float q = rintf(v * s);
    q = fminf(1.0f, fmaxf(-1.0f, q));
    return (int)q;
}

__global__ __launch_bounds__(256) void w_quant_kernel(const float* __restrict__ w,
                                                      int8_t* __restrict__ qw,
                                                      const float* __restrict__ params) {
    const float scale = params[0];
    const int stride = gridDim.x * 256;
    const float4* w4 = (const float4*)w;
    int* q4 = (int*)qw;
    for (int g = blockIdx.x * 256 + threadIdx.x; g < 16777216; g += stride) {
        float4 v = w4[g];
        int b0 = quant_w1(v.x, scale) & 255;
        int b1 = quant_w1(v.y, scale) & 255;
        int b2 = quant_w1(v.z, scale) & 255;
        int b3 = quant_w1(v.w, scale) & 255;
        q4[g] = b0 | (b1 << 8) | (b2 << 16) | (b3 << 24);
    }
}

// ---------------- int8 GEMM: 256x128 tile, 4 waves, 3-slot ring, 2 BLOCKS/CU, 32x32x32 --
// R9 structure (m114 two-block overlap) + mfma_i32_32x32x32_i8 (4404 vs 3944 TOPS, and
// 16 instead of 32 MFMA instrs/step). Register budget identical to R9 (frags 48 + acc 128)
// — R5's spill regression came from its E/O double-buffered fragment sets, not the shape.
// 4 waves (2M x 2N), per-wave 128x64 = 4 m-tiles x 2 n-tiles of 32x32, K-step 64B = 2 kh.
// 3-slot ring (slot = t%3), stage-2-ahead, 6 GLD/thread/step (4 A + 2 B).
// Per step t: { 12 ds_read slot t%3 | GLD6(t+2 -> (t+2)%3) | 16 MFMA |
//              vmcnt(6) [proves K(t+1)] | s_barrier [publishes slot (t+1)%3] }.
// A/B lane map (R5-verified exact-int): row/col = lane&31, k-byte = kh*32 + (lane>>5)*16.
// 16B-chunk XOR swizzle on global source + ds_read addr (rounds 1-9: 0 conflicts).
__global__ __launch_bounds__(256, 2) void gemm_i8_kernel(const int8_t* __restrict__ qx,
                                                         const int8_t* __restrict__ qw,
                                                         const float* __restrict__ inv_sx,
                                                         const float* __restrict__ params,
                                                         const float* __restrict__ bias,
                                                         float* __restrict__ y) {
    __shared__ __align__(16) int8_t lds[3][24576];   // per slot: A[256][64] + B[128][64]
    int8_t* L = &lds[0][0];

    const int tid = threadIdx.x;
    const int lane = tid & 63;
    const int w = tid >> 6;           // wave 0..3
    const int wr = w >> 1;            // 0..1  (M half)
    const int wc = w & 1;             // 0..1  (N half)
    const int wbase = w * 1024;       // wave-uniform LDS staging base (64 lanes x 16B)

    // XCD-aware bijective swizzle: 4096 blocks, 8 XCDs
    const int bid = blockIdx.x;
    const int swz = (bid & 7) * 512 + (bid >> 3);
    const int bn = swz & 127;         // 128 n-blocks (fast: consecutive share A-panel)
    const int bm = swz >> 7;          // 32 m-blocks

    const size_t arow0 = (size_t)bm * 256;
    const size_t bcol0 = (size_t)bn * 128;

    // staging: A 1024 chunks (4/thread, row stride 64), B 512 chunks (2/thread)
    const int r0 = tid >> 2;                       // 0..63
    const int kc0 = (tid & 3) ^ ((r0 >> 1) & 3);   // swizzled k-slot (involution)
    const int8_t* gA = qx + (arow0 + r0) * K_DIM + kc0 * 16;
    const int8_t* gB = qw + (bcol0 + r0) * K_DIM + kc0 * 16;

#define GLD(g, l)                                                                        \
    __builtin_amdgcn_global_load_lds((const __attribute__((address_space(1))) void*)(g), \
                                     (__attribute__((address_space(3))) void*)(l), 16, 0, 0)

// stage K-step ks into slot S: 4 A chunks + 2 B chunks per thread
#define GLD6(ks, S)                                                                      \
    do {                                                                                 \
        const size_t _o = (size_t)(ks) * 64;                                             \
        _Pragma("unroll") for (int _g = 0; _g < 4; ++_g)                                 \
            GLD(gA + _o + (size_t)_g * (64 * K_DIM),                                     \
                L + (S) * 24576 + _g * 4096 + wbase);                                    \
        _Pragma("unroll") for (int _h = 0; _h < 2; ++_h)                                 \
            GLD(gB + _o + (size_t)_h * (64 * K_DIM),                                     \
                L + (S) * 24576 + 16384 + _h * 4096 + wbase);                            \
    } while (0)

    // fragment ds_read offsets for 32x32x32 (within one 24KB slot):
    // lane row/col = lane&31, k-byte = kh*32 + (lane>>5)*16 -> 16B slot (kh*2+lh)
    const int l31 = lane & 31;
    const int lh = lane >> 5;         // 0..1
    int aoff[4][2], boff[2][2];
#pragma unroll
    for (int m = 0; m < 4; ++m) {
        const int ra = wr * 128 + m * 32 + l31;
#pragma unroll
        for (int kh = 0; kh < 2; ++kh) {
            const int s = (kh * 2 + lh) ^ ((ra >> 1) & 3);
            aoff[m][kh] = ra * 64 + s * 16;
        }
    }
#pragma unroll
    for (int n = 0; n < 2; ++n) {
        const int rb = wc * 64 + n * 32 + l31;
#pragma unroll
        for (int kh = 0; kh < 2; ++kh) {
            const int s = (kh * 2 + lh) ^ ((rb >> 1) & 3);
            boff[n][kh] = 16384 + rb * 64 + s * 16;
        }
    }

    v16i acc[4][2];
#pragma unroll
    for (int m = 0; m < 4; ++m)
#pragma unroll
        for (int n = 0; n < 2; ++n) acc[m][n] = (v16i)(0);

#define BARR()                                                                 \
    do {                                                                       \
        __builtin_amdgcn_s_barrier();                                          \
        __builtin_amdgcn_sched_barrier(0);                                     \
    } while (0)
#define VM(NSTR) asm volatile("s_waitcnt vmcnt(" NSTR ")" ::: "memory")

// One K-step: read 12 frags from slot CS, stage FKS (if STG), 16 MFMA, wait, barrier.
#define STEP(CS, FKS, FSL, STG, VMSTMT, DOBAR)                                 \
    do {                                                                       \
        const int8_t* _p = L + (CS) * 24576;                                   \
        v4i a[8], b[4];                                                        \
        _Pragma("unroll") for (int _m = 0; _m < 4; ++_m)                       \
            _Pragma("unroll") for (int _kh = 0; _kh < 2; ++_kh)                \
                a[_m * 2 + _kh] = *(const v4i*)(_p + aoff[_m][_kh]);           \
        _Pragma("unroll") for (int _n = 0; _n < 2; ++_n)                       \
            _Pragma("unroll") for (int _kh = 0; _kh < 2; ++_kh)                \
                b[_n * 2 + _kh] = *(const v4i*)(_p + boff[_n][_kh]);           \
        if (STG) GLD6(FKS, FSL);                                               \
        __builtin_amdgcn_s_setprio(1);                                         \
        _Pragma("unroll") for (int _m = 0; _m < 4; ++_m)                       \
            _Pragma("unroll") for (int _n = 0; _n < 2; ++_n)                   \
                _Pragma("unroll") for (int _kh = 0; _kh < 2; ++_kh)            \
                    acc[_m][_n] = __builtin_amdgcn_mfma_i32_32x32x32_i8(       \
                        a[_m * 2 + _kh], b[_n * 2 + _kh], acc[_m][_n],         \
                        0, 0, 0);                                              \
        __builtin_amdgcn_s_setprio(0);                                         \
        VMSTMT;                                                                \
        if (DOBAR) BARR();                                                     \
    } while (0)

    // prologue: stage K0->s0, K1->s1; vmcnt(6) proves K0; barrier publishes s0
    GLD6(0, 0);
    GLD6(1, 1);
    VM("6");
    BARR();

    // main loop: j=0..19, K-steps 3j..3j+2 (t=0..59), staging t+2 (slots 2,0,1)
#pragma unroll 1
    for (int j = 0; j < 20; ++j) {
        const int tb = 3 * j;
        STEP(0, tb + 2, 2, 1, VM("6"), 1);   // t=3j:   proves K(t+1)
        STEP(1, tb + 3, 0, 1, VM("6"), 1);
        STEP(2, tb + 4, 1, 1, VM("6"), 1);
    }
    // tail: t=60..63 (slots 0,1,2,0); K62 staged at t=60, K63 at t=61
    STEP(0, 62, 2, 1, VM("6"), 1);     // t=60: proves K61
    STEP(1, 63, 0, 1, VM("6"), 1);     // t=61: proves K62
    STEP(2, 0, 0, 0, VM("0"), 1);      // t=62: proves K63
    STEP(0, 0, 0, 0, (void)0, 0);      // t=63

    // epilogue: y = acc * inv_sx[row] * inv_sw + bias[col]
    // 32x32 C/D (R5-verified): col = lane&31, row = rb + 8*(g>>2) + (g&3),
    // rb = wr*128 + m*32 + 4*(lane>>5)
    const float invsw = params[1];
#pragma unroll
    for (int m = 0; m < 4; ++m) {
        const int rb = (int)arow0 + wr * 128 + m * 32 + 4 * lh;
        float isx[16];
#pragma unroll
        for (int g = 0; g < 16; ++g)
            isx[g] = inv_sx[rb + 8 * (g >> 2) + (g & 3)] * invsw;
#pragma unroll
        for (int n = 0; n < 2; ++n) {
            const int gcol = (int)bcol0 + wc * 64 + n * 32 + l31;
            const float bb = bias[gcol];
#pragma unroll
            for (int g = 0; g < 16; ++g) {
                const int grow = rb + 8 * (g >> 2) + (g & 3);
                y[(size_t)grow * N_COLS + gcol] = (float)acc[m][n][g] * isx[g] + bb;
            }
        }
    }
#undef GLD
#undef GLD6
#undef BARR
#undef VM
#undef STEP
}

// ---------------- launch ----------------
extern "C" void kernel_launch(void* const* d_in, const int* in_sizes, int n_in,
                              void* d_out, int out_size, void* d_ws, size_t ws_size,
                              hipStream_t stream) {
    const float* x    = (const float*)d_in[0];
    const float* wt   = (const float*)d_in[1];
    const float* bias = (const float*)d_in[2];
    float* y = (float*)d_out;

    if (ws_size < WS_NEED) return;

    char* ws = (char*)d_ws;
    float* partials = (float*)(ws + WS_PARTIALS);
    float* params   = (float*)(ws + WS_PARAMS);
    float* inv_sx   = (float*)(ws + WS_INVSX);
    int8_t* qx = (int8_t*)(ws + WS_QX);
    int8_t* qw = (int8_t*)(ws + WS_QW);

    hipLaunchKernelGGL(act_quant_kernel,   dim3(8192), dim3(256), 0, stream, x, qx, inv_sx);
    hipLaunchKernelGGL(wabs_partial_kernel,dim3(2048), dim3(256), 0, stream, wt, partials);
    hipLaunchKernelGGL(wfinal_kernel,      dim3(1),    dim3(256), 0, stream, partials, params);
    hipLaunchKernelGGL(w_quant_kernel,     dim3(4096), dim3(256), 0, stream, wt, qw, params);
    hipLaunchKernelGGL(gemm_i8_kernel,     dim3(4096), dim3(256), 0, stream,
                       qx, qw, inv_sx, params, bias, y);
}